// Round 13
// baseline (94.664 us; speedup 1.0000x reference)
//
#include <hip/hip_runtime.h>
#include <hip/hip_bf16.h>

#define DEVI static __device__ __forceinline__

typedef __attribute__((ext_vector_type(8))) short short8;
typedef __attribute__((ext_vector_type(16))) float f32x16;
typedef __attribute__((ext_vector_type(2))) unsigned int uintx2;

#define S_LEN 2048
#define D_DIM 128
#define NBATCH 16
// (1/sqrt(128)) * log2(e): base-2 softmax, scale folded into Q conversion
#define QSC ((float)(0.08838834764831845 * 1.4426950408889634))
// fixed softmax shift: P = 2^(score - 8); exact by shift-invariance
#define MFIX 8.0f
#define E8 0.00390625f  // 2^-8, weight of a masked (score 0) position

#if __has_builtin(__builtin_amdgcn_exp2f)
#define EXP2(x) __builtin_amdgcn_exp2f(x)
#else
#define EXP2(x) exp2f(x)
#endif

DEVI unsigned short f2bf(float x) {
  union { float f; unsigned int u; } a; a.f = x;
  unsigned int u = a.u;
  unsigned int r = (u + 0x7fffu + ((u >> 16) & 1u)) >> 16;
  return (unsigned short)r;
}

DEVI unsigned int cvtpk(float lo, float hi) {
  unsigned int r;
  asm volatile("v_cvt_pk_bf16_f32 %0, %1, %2" : "=v"(r) : "v"(lo), "v"(hi));
  return r;
}

// v_permlane32_swap_b32: post: a = {a.lo | b.lo}, b = {a.hi | b.hi}  (R4-verified)
DEVI void plswap(unsigned int& a, unsigned int& b) {
  uintx2 r = __builtin_amdgcn_permlane32_swap(a, b, false, false);
  a = r[0];
  b = r[1];
}

DEVI float xhalf_sum(float x) {
  union { float f; unsigned int u; } a, b;
  a.f = x; b.f = x;
  plswap(a.u, b.u);
  return a.f + b.f;
}

// ---------------- prepass ----------------

// blocks [0,1024): V [b][s][d] fp32 -> Vt TILE-MAJOR [b][kt][d 0..127][64 keys] bf16
//                  + per-64-row tile sums
// blocks [1024,3072): K fp32 -> bf16 (row-major unchanged)
__global__ void prep(const float* __restrict__ K, const float* __restrict__ V,
                     unsigned short* __restrict__ Kb, unsigned short* __restrict__ Vt,
                     float* __restrict__ Tsum) {
  __shared__ unsigned short t[64][68];
  const int tt = threadIdx.x;
  if (blockIdx.x >= 1024) {
    const int M4 = (NBATCH * S_LEN * D_DIM) / 4;
    for (int i = (blockIdx.x - 1024) * 256 + tt; i < M4; i += 2048 * 256) {
      const size_t idx = (size_t)i * 4;
      const float4 v = *reinterpret_cast<const float4*>(K + idx);
      ushort4 o;
      o.x = f2bf(v.x); o.y = f2bf(v.y); o.z = f2bf(v.z); o.w = f2bf(v.w);
      *reinterpret_cast<ushort4*>(Kb + idx) = o;
    }
    return;
  }
  const int bid = blockIdx.x;
  const int b = bid >> 6, rem = bid & 63;
  const int st = rem & 31, s0 = st * 64, d0 = (rem >> 5) * 64;
  const int r = tt >> 2, c = (tt & 3) * 16;
  const float* src = V + ((size_t)(b * S_LEN + s0 + r)) * D_DIM + d0 + c;
#pragma unroll
  for (int i = 0; i < 4; i++) {
    float4 v = reinterpret_cast<const float4*>(src)[i];
    t[r][c + 4 * i + 0] = f2bf(v.x);
    t[r][c + 4 * i + 1] = f2bf(v.y);
    t[r][c + 4 * i + 2] = f2bf(v.z);
    t[r][c + 4 * i + 3] = f2bf(v.w);
  }
  __syncthreads();
  // tile-major: Vt[((b*32+st)*128 + d)*64 + key]
  unsigned short* dst = Vt + (((size_t)(b * 32 + st)) * 128 + d0 + r) * 64 + c;
#pragma unroll
  for (int i = 0; i < 4; i++) {
    ushort4 o;
    o.x = t[c + 4 * i + 0][r];
    o.y = t[c + 4 * i + 1][r];
    o.z = t[c + 4 * i + 2][r];
    o.w = t[c + 4 * i + 3][r];
    reinterpret_cast<ushort4*>(dst)[i] = o;
  }
  if (tt < 64) {
    float s = 0.0f;
#pragma unroll 8
    for (int rr = 0; rr < 64; rr++) {
      union { float f; unsigned int u; } cv;
      cv.u = ((unsigned int)t[rr][tt]) << 16;
      s += cv.f;
    }
    Tsum[((size_t)b * 32 + st) * 128 + d0 + tt] = s;
  }
}

// SufV[b][t][d] = sum_{t' >= t} Tsum[b][t'][d]; SufV[b][32][d] = 0
__global__ void sufB(const float* __restrict__ Tsum, float* __restrict__ SufV) {
  const int b = blockIdx.x;
  const int d = threadIdx.x;
  float v[32];
#pragma unroll
  for (int t = 0; t < 32; t++) v[t] = Tsum[((size_t)b * 32 + t) * 128 + d];
  float run = 0.0f;
  SufV[((size_t)b * 33 + 32) * 128 + d] = 0.0f;
#pragma unroll
  for (int t = 31; t >= 0; t--) {
    run += v[t];
    SufV[((size_t)b * 33 + t) * 128 + d] = run;
  }
}

// ---------------- attention kernel ----------------

// Barrier-free tile body: K/V fragments loaded global->register (L2-resident),
// fixed-max softmax P = 2^(s-8). Lane-coalesced: K rows fully consumed by the
// kf x h pattern; V rows by kh x kl x h. No LDS, no syncthreads in the loop.
template <bool MASK>
DEVI void tile_body(const char* kt, const char* vt, const int krowoff,
                    const int vrowoff, const short8* qf, f32x16 (&acc)[4],
                    float& l_run, const int h, const int kh, const int qrow,
                    const int kvb) {
  short8 kfr[8];
#pragma unroll
  for (int kf = 0; kf < 8; kf++)
    kfr[kf] = *reinterpret_cast<const short8*>(kt + krowoff + 32 * kf);
  f32x16 sT;
#pragma unroll
  for (int r = 0; r < 16; r++) sT[r] = 0.0f;
  __builtin_amdgcn_s_setprio(1);
#pragma unroll
  for (int kf = 0; kf < 8; kf++)
    sT = __builtin_amdgcn_mfma_f32_32x32x16_bf16(kfr[kf], qf[kf], sT, 0, 0, 0);
  __builtin_amdgcn_s_setprio(0);
  // V fragments issued before the softmax VALU: L2 latency hides under it
  short8 vfr[8];
#pragma unroll
  for (int kl = 0; kl < 2; kl++)
#pragma unroll
    for (int nt = 0; nt < 4; nt++)
      vfr[kl * 4 + nt] = *reinterpret_cast<const short8*>(
          vt + vrowoff + 32 * kl + 4096 * nt);
  if (MASK) {
#pragma unroll
    for (int r = 0; r < 16; r++) {
      int kvg = kvb + (r & 3) + 8 * (r >> 2) + 4 * h;
      if (kvg > qrow) sT[r] = 0.0f;  // multiplicative mask; exp gives 2^-8
    }
  }
#pragma unroll
  for (int r = 0; r < 16; r++) sT[r] = EXP2(sT[r] - MFIX);
  float ts[8];
#pragma unroll
  for (int r = 0; r < 8; r++) ts[r] = sT[r] + sT[r + 8];
#pragma unroll
  for (int r = 0; r < 4; r++) ts[r] = ts[r] + ts[r + 4];
  float sum = (ts[0] + ts[1]) + (ts[2] + ts[3]);
  sum = xhalf_sum(sum);
  l_run += sum;
  // pack P -> bf16 A-fragments: u[0]={a.lo|b.lo}, u[2]={a.hi|b.hi} (R4-verified)
#pragma unroll
  for (int kl = 0; kl < 2; kl++) {
    const int ra = 8 * kl;
    const int rb = 8 * kl + 4;
    unsigned int a0 = cvtpk(sT[ra + 0], sT[ra + 1]);
    unsigned int a1 = cvtpk(sT[ra + 2], sT[ra + 3]);
    unsigned int b0 = cvtpk(sT[rb + 0], sT[rb + 1]);
    unsigned int b1 = cvtpk(sT[rb + 2], sT[rb + 3]);
    plswap(a0, b0);
    plswap(a1, b1);
    union { short8 v; unsigned int u[4]; } pa;
    pa.u[0] = a0; pa.u[1] = a1; pa.u[2] = b0; pa.u[3] = b1;
    __builtin_amdgcn_s_setprio(1);
#pragma unroll
    for (int nt = 0; nt < 4; nt++)
      acc[nt] = __builtin_amdgcn_mfma_f32_32x32x16_bf16(pa.v, vfr[kl * 4 + nt],
                                                        acc[nt], 0, 0, 0);
    __builtin_amdgcn_s_setprio(0);
  }
}

// LDS: merge-only. 6 partial regions (16KB each) + l rows (1KB) = 99328 B.
#define SMEM_BYTES 99328

DEVI void run_strip(int j, int b, char* smem, const float* __restrict__ Q,
                    const char* kbB, const char* vbB,
                    const float* __restrict__ SufV, float* __restrict__ out,
                    int qs, int kh, int grp, int ln31, int h) {
  const int q0 = j * 64;
  const int kv_end = q0 + 64;
  const int qrow = q0 + 32 * qs + ln31;
  const int pidx = kh * 2 + grp;

  // Q fragments (B-operand): frag kf element jj <-> d = 16*kf + 8*h + jj
  short8 qf[8];
  {
    const float* qsrc = Q + ((size_t)b * S_LEN + qrow) * D_DIM + 8 * h;
#pragma unroll
    for (int kf = 0; kf < 8; kf++) {
      float4 a = *reinterpret_cast<const float4*>(qsrc + 16 * kf);
      float4 d = *reinterpret_cast<const float4*>(qsrc + 16 * kf + 4);
      union { short8 v; unsigned int u[4]; } q8;
      q8.u[0] = cvtpk(a.x * QSC, a.y * QSC);
      q8.u[1] = cvtpk(a.z * QSC, a.w * QSC);
      q8.u[2] = cvtpk(d.x * QSC, d.y * QSC);
      q8.u[3] = cvtpk(d.z * QSC, d.w * QSC);
      qf[kf] = q8.v;
    }
  }

  f32x16 acc[4];
#pragma unroll
  for (int nt = 0; nt < 4; nt++)
#pragma unroll
    for (int rr = 0; rr < 16; rr++) acc[nt][rr] = 0.0f;
  float l_run = 0.0f;

  const int krowoff = (ln31 + 32 * kh) * 256 + 16 * h;  // K: row x 256B + d-bytes
  const int vrowoff = ln31 * 128 + 64 * kh + 16 * h;    // V: d-row x 128B + key-bytes

  // barrier-free loop: this wave owns tiles of parity grp
  for (int t = grp; t <= j; t += 2) {
    const char* kt = kbB + (size_t)t * 16384;
    const char* vt = vbB + (size_t)t * 16384;
    if (t == j)
      tile_body<true>(kt, vt, krowoff, vrowoff, qf, acc, l_run, h, kh, qrow,
                      t * 64 + 32 * kh);
    else
      tile_body<false>(kt, vt, krowoff, vrowoff, qf, acc, l_run, h, kh, qrow,
                       t * 64 + 32 * kh);
  }

  // merge: waves pidx!=0 publish partials; pidx==0 reduces (fixed-max: plain sums)
  float* lsh = (float*)(smem + 98304);
  if (pidx != 0) {
    float* reg = (float*)smem + (qs * 3 + pidx - 1) * 4096;
#pragma unroll
    for (int nt = 0; nt < 4; nt++)
#pragma unroll
      for (int rr = 0; rr < 16; rr++) {
        int cr = (rr & 3) + 8 * (rr >> 2) + 4 * h;
        reg[cr * 128 + ln31 + 32 * nt] = acc[nt][rr];
      }
    if (h == 0) lsh[(qs * 3 + pidx - 1) * 32 + ln31] = l_run;
  }
  __syncthreads();
  if (pidx == 0) {
    float l_tot = l_run + lsh[(qs * 3 + 0) * 32 + ln31] +
                  lsh[(qs * 3 + 1) * 32 + ln31] + lsh[(qs * 3 + 2) * 32 + ln31] +
                  (float)(S_LEN - kv_end) * E8;
    const float* sv = SufV + ((size_t)b * 33 + (kv_end >> 6)) * 128;
    const float* r0 = (float*)smem + (qs * 3 + 0) * 4096;
    const float* r1 = (float*)smem + (qs * 3 + 1) * 4096;
    const float* r2 = (float*)smem + (qs * 3 + 2) * 4096;
    float* ob = out + ((size_t)b * S_LEN + q0 + 32 * qs) * D_DIM + ln31;
#pragma unroll
    for (int nt = 0; nt < 4; nt++) {
      float svv = sv[ln31 + 32 * nt];
#pragma unroll
      for (int rr = 0; rr < 16; rr++) {
        int cr = (rr & 3) + 8 * (rr >> 2) + 4 * h;
        int cidx = cr * 128 + ln31 + 32 * nt;
        float v = acc[nt][rr] + r0[cidx] + r1[cidx] + r2[cidx] + E8 * svv;
        ob[(size_t)cr * D_DIM + 32 * nt] = v / __shfl(l_tot, cr);
      }
    }
  }
  __syncthreads();  // regions reused by the next strip
}

__global__ __launch_bounds__(512, 2) void attn_kernel(
    const float* __restrict__ Q, const unsigned short* __restrict__ Kb,
    const unsigned short* __restrict__ Vt, const float* __restrict__ SufV,
    float* __restrict__ out) {
  __shared__ __align__(16) char smem[SMEM_BYTES];

  const int tid = threadIdx.x;
  const int w = tid >> 6, lane = tid & 63;
  const int ln31 = lane & 31, h = lane >> 5;
  const int qs = w >> 2;        // q half
  const int kh = (w >> 1) & 1;  // key half of each tile
  const int grp = w & 1;        // tile parity

  // decode: XCD x owns batches {2x,2x+1}; block does strips (31-p, p) of batch b
  const int bid = blockIdx.x;
  const int x = bid & 7, idx = bid >> 3;
  const int b = 2 * x + (idx & 1);
  const int p = idx >> 1;

  const char* kbB = (const char*)(Kb + (size_t)b * S_LEN * D_DIM);
  const char* vbB = (const char*)Vt + (size_t)b * (S_LEN * D_DIM * 2);

  run_strip(31 - p, b, smem, Q, kbB, vbB, SufV, out, qs, kh, grp, ln31, h);
  run_strip(p, b, smem, Q, kbB, vbB, SufV, out, qs, kh, grp, ln31, h);
}

// ---------------- launcher ----------------

extern "C" void kernel_launch(void* const* d_in, const int* in_sizes, int n_in,
                              void* d_out, int out_size, void* d_ws, size_t ws_size,
                              hipStream_t stream) {
  const float* Q = (const float*)d_in[0];
  const float* K = (const float*)d_in[1];
  const float* V = (const float*)d_in[2];
  float* out = (float*)d_out;

  char* ws = (char*)d_ws;
  unsigned short* Kb = (unsigned short*)ws;                 // 8 MiB
  unsigned short* Vt = Kb + 4194304;                        // 8 MiB (tile-major)
  float* Tsum = (float*)(ws + 16777216);                    // 256 KiB
  float* SufV = Tsum + 65536;                               // 264 KiB

  prep<<<3072, 256, 0, stream>>>(K, V, Kb, Vt, Tsum);
  sufB<<<16, 128, 0, stream>>>(Tsum, SufV);
  attn_kernel<<<256, 512, 0, stream>>>(Q, Kb, Vt, SufV, out);
}

// Round 14
// 55.623 us; speedup vs baseline: 1.7019x; 1.7019x over previous
//
#include <hip/hip_runtime.h>
#include <hip/hip_bf16.h>

#define DEVI static __device__ __forceinline__

typedef __attribute__((ext_vector_type(8))) short short8;
typedef __attribute__((ext_vector_type(16))) float f32x16;
typedef __attribute__((ext_vector_type(2))) unsigned int uintx2;

#define S_LEN 2048
#define D_DIM 128
#define NBATCH 16
// (1/sqrt(128)) * log2(e): base-2 softmax, scale folded into Q conversion
#define QSC ((float)(0.08838834764831845 * 1.4426950408889634))
// fixed softmax shift: P = 2^(score - 8); exact by shift-invariance
#define MFIX 8.0f
#define E8 0.00390625f  // 2^-8, weight of a masked (score 0) position

#if __has_builtin(__builtin_amdgcn_exp2f)
#define EXP2(x) __builtin_amdgcn_exp2f(x)
#else
#define EXP2(x) exp2f(x)
#endif

DEVI unsigned short f2bf(float x) {
  union { float f; unsigned int u; } a; a.f = x;
  unsigned int u = a.u;
  unsigned int r = (u + 0x7fffu + ((u >> 16) & 1u)) >> 16;
  return (unsigned short)r;
}

DEVI unsigned int cvtpk(float lo, float hi) {
  unsigned int r;
  asm volatile("v_cvt_pk_bf16_f32 %0, %1, %2" : "=v"(r) : "v"(lo), "v"(hi));
  return r;
}

// v_permlane32_swap_b32: post: a = {a.lo | b.lo}, b = {a.hi | b.hi}  (R4-verified)
DEVI void plswap(unsigned int& a, unsigned int& b) {
  uintx2 r = __builtin_amdgcn_permlane32_swap(a, b, false, false);
  a = r[0];
  b = r[1];
}

DEVI float xhalf_sum(float x) {
  union { float f; unsigned int u; } a, b;
  a.f = x; b.f = x;
  plswap(a.u, b.u);
  return a.f + b.f;
}

// ---------------- prepass ----------------

// blocks [0,1024): V [b][s][d] fp32 -> Vt TILE-MAJOR [b][kt][d 0..127][64 keys] bf16
//                  + per-64-row tile sums
// blocks [1024,3072): K fp32 -> bf16 (row-major unchanged)
__global__ void prep(const float* __restrict__ K, const float* __restrict__ V,
                     unsigned short* __restrict__ Kb, unsigned short* __restrict__ Vt,
                     float* __restrict__ Tsum) {
  __shared__ unsigned short t[64][68];
  const int tt = threadIdx.x;
  if (blockIdx.x >= 1024) {
    const int M4 = (NBATCH * S_LEN * D_DIM) / 4;
    for (int i = (blockIdx.x - 1024) * 256 + tt; i < M4; i += 2048 * 256) {
      const size_t idx = (size_t)i * 4;
      const float4 v = *reinterpret_cast<const float4*>(K + idx);
      ushort4 o;
      o.x = f2bf(v.x); o.y = f2bf(v.y); o.z = f2bf(v.z); o.w = f2bf(v.w);
      *reinterpret_cast<ushort4*>(Kb + idx) = o;
    }
    return;
  }
  const int bid = blockIdx.x;
  const int b = bid >> 6, rem = bid & 63;
  const int st = rem & 31, s0 = st * 64, d0 = (rem >> 5) * 64;
  const int r = tt >> 2, c = (tt & 3) * 16;
  const float* src = V + ((size_t)(b * S_LEN + s0 + r)) * D_DIM + d0 + c;
#pragma unroll
  for (int i = 0; i < 4; i++) {
    float4 v = reinterpret_cast<const float4*>(src)[i];
    t[r][c + 4 * i + 0] = f2bf(v.x);
    t[r][c + 4 * i + 1] = f2bf(v.y);
    t[r][c + 4 * i + 2] = f2bf(v.z);
    t[r][c + 4 * i + 3] = f2bf(v.w);
  }
  __syncthreads();
  // tile-major: Vt[((b*32+st)*128 + d)*64 + key]
  unsigned short* dst = Vt + (((size_t)(b * 32 + st)) * 128 + d0 + r) * 64 + c;
#pragma unroll
  for (int i = 0; i < 4; i++) {
    ushort4 o;
    o.x = t[c + 4 * i + 0][r];
    o.y = t[c + 4 * i + 1][r];
    o.z = t[c + 4 * i + 2][r];
    o.w = t[c + 4 * i + 3][r];
    reinterpret_cast<ushort4*>(dst)[i] = o;
  }
  if (tt < 64) {
    float s = 0.0f;
#pragma unroll 8
    for (int rr = 0; rr < 64; rr++) {
      union { float f; unsigned int u; } cv;
      cv.u = ((unsigned int)t[rr][tt]) << 16;
      s += cv.f;
    }
    Tsum[((size_t)b * 32 + st) * 128 + d0 + tt] = s;
  }
}

// SufV[b][t][d] = sum_{t' >= t} Tsum[b][t'][d]; SufV[b][32][d] = 0
__global__ void sufB(const float* __restrict__ Tsum, float* __restrict__ SufV) {
  const int b = blockIdx.x;
  const int d = threadIdx.x;
  float v[32];
#pragma unroll
  for (int t = 0; t < 32; t++) v[t] = Tsum[((size_t)b * 32 + t) * 128 + d];
  float run = 0.0f;
  SufV[((size_t)b * 33 + 32) * 128 + d] = 0.0f;
#pragma unroll
  for (int t = 31; t >= 0; t--) {
    run += v[t];
    SufV[((size_t)b * 33 + t) * 128 + d] = run;
  }
}

// ---------------- attention kernel ----------------

#define AS1 __attribute__((address_space(1)))
#define AS3 __attribute__((address_space(3)))

DEVI short8 ldK(const char* ldsK, int row, int off) {
  int addr = row * 256 + (off ^ ((row & 15) << 4));
  return *reinterpret_cast<const short8*>(ldsK + addr);
}
DEVI short8 ldV(const char* ldsV, int row, int off) {
  int addr = row * 128 + (off ^ ((row & 7) << 4));
  return *reinterpret_cast<const short8*>(ldsV + addr);
}

// fixed-max tile body, split QK chains: P = 2^(s-8)  (R9-verified + 2-chain QK)
template <bool MASK>
DEVI void tile_body(const char* cb, const short8* qf, f32x16 (&acc)[4],
                    float& l_run, const int ln31, const int h, const int kh,
                    const int qrow, const int kvb) {
  f32x16 sA, sB;
#pragma unroll
  for (int r = 0; r < 16; r++) { sA[r] = 0.0f; sB[r] = 0.0f; }
  __builtin_amdgcn_s_setprio(1);
#pragma unroll
  for (int kf = 0; kf < 8; kf += 2) {
    short8 a0 = ldK(cb, ln31 + 32 * kh, 32 * kf + 16 * h);
    short8 a1 = ldK(cb, ln31 + 32 * kh, 32 * (kf + 1) + 16 * h);
    sA = __builtin_amdgcn_mfma_f32_32x32x16_bf16(a0, qf[kf], sA, 0, 0, 0);
    sB = __builtin_amdgcn_mfma_f32_32x32x16_bf16(a1, qf[kf + 1], sB, 0, 0, 0);
  }
  __builtin_amdgcn_s_setprio(0);
  f32x16 sT;
#pragma unroll
  for (int r = 0; r < 16; r++) sT[r] = sA[r] + sB[r];
  if (MASK) {
#pragma unroll
    for (int r = 0; r < 16; r++) {
      int kvg = kvb + (r & 3) + 8 * (r >> 2) + 4 * h;
      if (kvg > qrow) sT[r] = 0.0f;  // multiplicative mask; exp gives 2^-8
    }
  }
#pragma unroll
  for (int r = 0; r < 16; r++) sT[r] = EXP2(sT[r] - MFIX);
  float ts[8];
#pragma unroll
  for (int r = 0; r < 8; r++) ts[r] = sT[r] + sT[r + 8];
#pragma unroll
  for (int r = 0; r < 4; r++) ts[r] = ts[r] + ts[r + 4];
  float sum = (ts[0] + ts[1]) + (ts[2] + ts[3]);
  sum = xhalf_sum(sum);
  l_run += sum;
  // pack P -> bf16 A-fragments: u[0]={a.lo|b.lo}, u[2]={a.hi|b.hi} (R4-verified)
#pragma unroll
  for (int kl = 0; kl < 2; kl++) {
    const int ra = 8 * kl;
    const int rb = 8 * kl + 4;
    unsigned int a0 = cvtpk(sT[ra + 0], sT[ra + 1]);
    unsigned int a1 = cvtpk(sT[ra + 2], sT[ra + 3]);
    unsigned int b0 = cvtpk(sT[rb + 0], sT[rb + 1]);
    unsigned int b1 = cvtpk(sT[rb + 2], sT[rb + 3]);
    plswap(a0, b0);
    plswap(a1, b1);
    union { short8 v; unsigned int u[4]; } pa;
    pa.u[0] = a0; pa.u[1] = a1; pa.u[2] = b0; pa.u[3] = b1;
    const int vboff = 64 * kh + 32 * kl + 16 * h;
    __builtin_amdgcn_s_setprio(1);
#pragma unroll
    for (int nt = 0; nt < 4; nt++) {
      short8 vb = ldV(cb + 16384, ln31 + 32 * nt, vboff);
      acc[nt] = __builtin_amdgcn_mfma_f32_32x32x16_bf16(pa.v, vb, acc[nt], 0, 0, 0);
    }
    __builtin_amdgcn_s_setprio(0);
  }
}

// LDS: 4 tile buffers (2 dbuf x 2 grp) of 32KB (K 16K + V 16K) = 128KB,
// overlaid in epilogue by 8 partials (32x128 f32 = 16KB each) + l rows (1KB).
#define SMEM_BYTES 132096

struct WaveCtx {
  int w, lane, ln31, h, qs, grp, kh, tsel, dstpart;
  int off[8];
  const char* tbase;
};

// UNCONDITIONAL 8-load stage (uniform vmcnt bookkeeping; caller clamps t)
DEVI void stage_tile(char* smem, const WaveCtx& c, int t, int bi) {
  const char* src = c.tbase + (size_t)t * 16384;
  const int dbase = bi * 65536 + c.tsel * 32768 + c.dstpart;
#pragma unroll
  for (int i = 0; i < 8; i++) {
    __builtin_amdgcn_global_load_lds((const AS1 unsigned int*)(src + c.off[i]),
                                     (AS3 unsigned int*)(smem + dbase + i * 1024),
                                     16, 0, 0);
  }
}

DEVI void run_strip(int j, int b, char* smem, const WaveCtx& c,
                    const float* __restrict__ Q, const float* __restrict__ SufV,
                    float* __restrict__ out) {
  const int q0 = j * 64;
  const int kv_end = q0 + 64;
  const int qrow = q0 + 32 * c.qs + c.ln31;

  // Q fragments (B-operand): frag kf element jj <-> d = 16*kf + 8*h + jj
  short8 qf[8];
  {
    const float* qsrc = Q + ((size_t)b * S_LEN + qrow) * D_DIM + 8 * c.h;
#pragma unroll
    for (int kf = 0; kf < 8; kf++) {
      float4 a = *reinterpret_cast<const float4*>(qsrc + 16 * kf);
      float4 d = *reinterpret_cast<const float4*>(qsrc + 16 * kf + 4);
      union { short8 v; unsigned int u[4]; } q8;
      q8.u[0] = cvtpk(a.x * QSC, a.y * QSC);
      q8.u[1] = cvtpk(a.z * QSC, a.w * QSC);
      q8.u[2] = cvtpk(d.x * QSC, d.y * QSC);
      q8.u[3] = cvtpk(d.z * QSC, d.w * QSC);
      qf[kf] = q8.v;
    }
  }

  f32x16 acc[4];
#pragma unroll
  for (int nt = 0; nt < 4; nt++)
#pragma unroll
    for (int rr = 0; rr < 16; rr++) acc[nt][rr] = 0.0f;
  float l_run = 0.0f;

  // pipelined phase loop: counted vmcnt(8) keeps next-tile loads in flight
  // across the barrier (every wave issues exactly 8 loads per phase).
  const int nph = (j >> 1) + 1;
  {
    int t0 = c.tsel;
    if (t0 > j) t0 = j;
    stage_tile(smem, c, t0, 0);
  }
  int bi = 0;
  for (int ph = 0; ph < nph; ph++) {
    int tn = 2 * (ph + 1) + c.tsel;
    if (tn > j) tn = j;                  // clamp: uniform load count, data unused
    stage_tile(smem, c, tn, bi ^ 1);
    // my previous-phase 8 loads done (only the 8 just-issued remain):
    asm volatile("s_waitcnt vmcnt(8)" ::: "memory");
    __builtin_amdgcn_sched_barrier(0);
    __builtin_amdgcn_s_barrier();        // RAW publish: current buffers ready
    __builtin_amdgcn_sched_barrier(0);
    const int t = 2 * ph + c.grp;
    if (t <= j) {
      const char* cb = smem + bi * 65536 + c.grp * 32768;
      if (t == j)
        tile_body<true>(cb, qf, acc, l_run, c.ln31, c.h, c.kh, qrow,
                        t * 64 + 32 * c.kh);
      else
        tile_body<false>(cb, qf, acc, l_run, c.ln31, c.h, c.kh, qrow,
                         t * 64 + 32 * c.kh);
    }
    __builtin_amdgcn_s_barrier();        // WAR protect: done reading bi
    __builtin_amdgcn_sched_barrier(0);
    bi ^= 1;
  }
  __syncthreads();  // full drain (incl. clamped garbage stage) before overlay

  // epilogue: all 8 waves write partial acc + l; then each wave reduces one
  // (qs, 32-col slice) of the 4 partials (fixed-max => plain sums)
  float* pbase = (float*)smem + c.w * 4096;
#pragma unroll
  for (int nt = 0; nt < 4; nt++)
#pragma unroll
    for (int rr = 0; rr < 16; rr++) {
      int cr = (rr & 3) + 8 * (rr >> 2) + 4 * c.h;
      pbase[cr * 128 + c.ln31 + 32 * nt] = acc[nt][rr];
    }
  float* lbase = (float*)(smem + 131072) + c.w * 32;
  if (c.h == 0) lbase[c.ln31] = l_run;
  __syncthreads();

  const int s = c.w & 3;
  const float* P0 = (float*)smem + (c.qs * 4) * 4096;
  const float* L0 = (float*)(smem + 131072) + (c.qs * 4) * 32;
  float l_tot = L0[c.ln31] + L0[32 + c.ln31] + L0[64 + c.ln31] + L0[96 + c.ln31];
  l_tot += (float)(S_LEN - kv_end) * E8;
  const float svv = SufV[((size_t)b * 33 + (kv_end >> 6)) * 128 + 32 * s + c.ln31];
  float* ob = out + ((size_t)b * S_LEN + q0 + 32 * c.qs) * D_DIM + 32 * s + c.ln31;
#pragma unroll
  for (int rr = 0; rr < 16; rr++) {
    int cr = (rr & 3) + 8 * (rr >> 2) + 4 * c.h;
    int cidx = cr * 128 + 32 * s + c.ln31;
    float v = P0[cidx] + P0[4096 + cidx] + P0[8192 + cidx] + P0[12288 + cidx];
    float lq = __shfl(l_tot, cr);
    ob[(size_t)cr * D_DIM] = (v + E8 * svv) / lq;
  }
  __syncthreads();  // protect overlay before next strip's staging
}

__global__ __launch_bounds__(512, 2) void attn_kernel(
    const float* __restrict__ Q, const unsigned short* __restrict__ Kb,
    const unsigned short* __restrict__ Vt, const float* __restrict__ SufV,
    float* __restrict__ out) {
  __shared__ __align__(16) char smem[SMEM_BYTES];

  WaveCtx c;
  const int tid = threadIdx.x;
  c.w = tid >> 6;
  c.lane = tid & 63;
  c.ln31 = c.lane & 31;
  c.h = c.lane >> 5;
  c.qs = c.w >> 2;
  c.grp = (c.w >> 1) & 1;
  c.kh = c.w & 1;
  c.tsel = c.w >> 2;  // staging: waves 0-3 -> even tile, 4-7 -> odd tile
  const int part = c.w & 3;

  // decode: XCD x owns batches {2x,2x+1}; block = (b, pair p): strips 31-p and p
  const int bid = blockIdx.x;
  const int x = bid & 7, idx = bid >> 3;
  const int b = 2 * x + (idx & 1);
  const int p = idx >> 1;

  // per-wave staging constants (R8/R9-verified swizzle formulas, imm=0)
  if (part < 2) {
#pragma unroll
    for (int i = 0; i < 8; i++) {
      int L = (part * 8 + i) * 1024 + c.lane * 16;
      int row = L >> 8;
      c.off[i] = row * 256 + ((L & 255) ^ ((row & 15) << 4));
    }
    c.tbase = (const char*)(Kb + (size_t)b * S_LEN * D_DIM);
    c.dstpart = part * 8192;
  } else {
#pragma unroll
    for (int i = 0; i < 8; i++) {
      int L = ((part - 2) * 8 + i) * 1024 + c.lane * 16;
      int row = L >> 7;
      c.off[i] = (L & ~127) + ((L & 127) ^ ((row & 7) << 4));
    }
    c.tbase = (const char*)Vt + (size_t)b * (S_LEN * D_DIM * 2);
    c.dstpart = 16384 + (part - 2) * 8192;
  }

  run_strip(31 - p, b, smem, c, Q, SufV, out);
  run_strip(p, b, smem, c, Q, SufV, out);
}

// ---------------- launcher ----------------

extern "C" void kernel_launch(void* const* d_in, const int* in_sizes, int n_in,
                              void* d_out, int out_size, void* d_ws, size_t ws_size,
                              hipStream_t stream) {
  const float* Q = (const float*)d_in[0];
  const float* K = (const float*)d_in[1];
  const float* V = (const float*)d_in[2];
  float* out = (float*)d_out;

  char* ws = (char*)d_ws;
  unsigned short* Kb = (unsigned short*)ws;                 // 8 MiB
  unsigned short* Vt = Kb + 4194304;                        // 8 MiB (tile-major)
  float* Tsum = (float*)(ws + 16777216);                    // 256 KiB
  float* SufV = Tsum + 65536;                               // 264 KiB

  prep<<<3072, 256, 0, stream>>>(K, V, Kb, Vt, Tsum);
  sufB<<<16, 128, 0, stream>>>(Tsum, SufV);
  attn_kernel<<<256, 512, 0, stream>>>(Q, Kb, Vt, SufV, out);
}

// Round 15
// 53.395 us; speedup vs baseline: 1.7729x; 1.0417x over previous
//
#include <hip/hip_runtime.h>
#include <hip/hip_bf16.h>

#define DEVI static __device__ __forceinline__

typedef __attribute__((ext_vector_type(8))) short short8;
typedef __attribute__((ext_vector_type(16))) float f32x16;
typedef __attribute__((ext_vector_type(2))) unsigned int uintx2;

#define S_LEN 2048
#define D_DIM 128
#define NBATCH 16
// (1/sqrt(128)) * log2(e): base-2 softmax, scale folded into Q conversion
#define QSC ((float)(0.08838834764831845 * 1.4426950408889634))
// fixed softmax shift: P = 2^(score - 8); exact by shift-invariance
#define MFIX 8.0f
#define E8 0.00390625f  // 2^-8, weight of a masked (score 0) position

#if __has_builtin(__builtin_amdgcn_exp2f)
#define EXP2(x) __builtin_amdgcn_exp2f(x)
#else
#define EXP2(x) exp2f(x)
#endif

DEVI unsigned short f2bf(float x) {
  union { float f; unsigned int u; } a; a.f = x;
  unsigned int u = a.u;
  unsigned int r = (u + 0x7fffu + ((u >> 16) & 1u)) >> 16;
  return (unsigned short)r;
}

DEVI unsigned int cvtpk(float lo, float hi) {
  unsigned int r;
  asm volatile("v_cvt_pk_bf16_f32 %0, %1, %2" : "=v"(r) : "v"(lo), "v"(hi));
  return r;
}

// v_permlane32_swap_b32: post: a = {a.lo | b.lo}, b = {a.hi | b.hi}  (R4-verified)
DEVI void plswap(unsigned int& a, unsigned int& b) {
  uintx2 r = __builtin_amdgcn_permlane32_swap(a, b, false, false);
  a = r[0];
  b = r[1];
}

DEVI float xhalf_sum(float x) {
  union { float f; unsigned int u; } a, b;
  a.f = x; b.f = x;
  plswap(a.u, b.u);
  return a.f + b.f;
}

// ---------------- prepass ----------------

// blocks [0,1024): V [b][s][d] fp32 -> Vt TILE-MAJOR-128: [b][t128][d 0..127][128 keys]
//                  bf16 (32KB per 128-key tile) + per-64-row tile sums
// blocks [1024,3072): K fp32 -> bf16 (row-major unchanged)
__global__ void prep(const float* __restrict__ K, const float* __restrict__ V,
                     unsigned short* __restrict__ Kb, unsigned short* __restrict__ Vt,
                     float* __restrict__ Tsum) {
  __shared__ unsigned short t[64][68];
  const int tt = threadIdx.x;
  if (blockIdx.x >= 1024) {
    const int M4 = (NBATCH * S_LEN * D_DIM) / 4;
    for (int i = (blockIdx.x - 1024) * 256 + tt; i < M4; i += 2048 * 256) {
      const size_t idx = (size_t)i * 4;
      const float4 v = *reinterpret_cast<const float4*>(K + idx);
      ushort4 o;
      o.x = f2bf(v.x); o.y = f2bf(v.y); o.z = f2bf(v.z); o.w = f2bf(v.w);
      *reinterpret_cast<ushort4*>(Kb + idx) = o;
    }
    return;
  }
  const int bid = blockIdx.x;
  const int b = bid >> 6, rem = bid & 63;
  const int st = rem & 31, s0 = st * 64, d0 = (rem >> 5) * 64;
  const int r = tt >> 2, c = (tt & 3) * 16;
  const float* src = V + ((size_t)(b * S_LEN + s0 + r)) * D_DIM + d0 + c;
#pragma unroll
  for (int i = 0; i < 4; i++) {
    float4 v = reinterpret_cast<const float4*>(src)[i];
    t[r][c + 4 * i + 0] = f2bf(v.x);
    t[r][c + 4 * i + 1] = f2bf(v.y);
    t[r][c + 4 * i + 2] = f2bf(v.z);
    t[r][c + 4 * i + 3] = f2bf(v.w);
  }
  __syncthreads();
  // 128-key tile-major: Vt[((b*16 + (st>>1))*128 + d)*128 + (st&1)*64 + key]
  unsigned short* dst =
      Vt + (((size_t)(b * 16 + (st >> 1))) * 128 + d0 + r) * 128 + (st & 1) * 64 + c;
#pragma unroll
  for (int i = 0; i < 4; i++) {
    ushort4 o;
    o.x = t[c + 4 * i + 0][r];
    o.y = t[c + 4 * i + 1][r];
    o.z = t[c + 4 * i + 2][r];
    o.w = t[c + 4 * i + 3][r];
    reinterpret_cast<ushort4*>(dst)[i] = o;
  }
  if (tt < 64) {
    float s = 0.0f;
#pragma unroll 8
    for (int rr = 0; rr < 64; rr++) {
      union { float f; unsigned int u; } cv;
      cv.u = ((unsigned int)t[rr][tt]) << 16;
      s += cv.f;
    }
    Tsum[((size_t)b * 32 + st) * 128 + d0 + tt] = s;
  }
}

// SufV[b][t][d] = sum_{t' >= t} Tsum[b][t'][d]; SufV[b][32][d] = 0  (64-granular)
__global__ void sufB(const float* __restrict__ Tsum, float* __restrict__ SufV) {
  const int b = blockIdx.x;
  const int d = threadIdx.x;
  float v[32];
#pragma unroll
  for (int t = 0; t < 32; t++) v[t] = Tsum[((size_t)b * 32 + t) * 128 + d];
  float run = 0.0f;
  SufV[((size_t)b * 33 + 32) * 128 + d] = 0.0f;
#pragma unroll
  for (int t = 31; t >= 0; t--) {
    run += v[t];
    SufV[((size_t)b * 33 + t) * 128 + d] = run;
  }
}

// ---------------- attention kernel ----------------

#define AS1 __attribute__((address_space(1)))
#define AS3 __attribute__((address_space(3)))

// fixed-max tile body: P = 2^(s-8); hoisted LDS addresses (ka/va, static idx)
template <bool MASK>
DEVI void tile_body(const char* kb, const char* vb, const int* ka, const int* va,
                    const short8* qf, f32x16 (&acc)[4], float& l_run,
                    const int h, const int qrow, const int kvb) {
  f32x16 sT;
#pragma unroll
  for (int r = 0; r < 16; r++) sT[r] = 0.0f;
  __builtin_amdgcn_s_setprio(1);
#pragma unroll
  for (int kf = 0; kf < 8; kf++) {
    short8 af = *reinterpret_cast<const short8*>(kb + ka[kf]);
    sT = __builtin_amdgcn_mfma_f32_32x32x16_bf16(af, qf[kf], sT, 0, 0, 0);
  }
  __builtin_amdgcn_s_setprio(0);
  if (MASK) {
#pragma unroll
    for (int r = 0; r < 16; r++) {
      int kvg = kvb + (r & 3) + 8 * (r >> 2) + 4 * h;
      if (kvg > qrow) sT[r] = 0.0f;  // multiplicative mask; exp gives 2^-8
    }
  }
#pragma unroll
  for (int r = 0; r < 16; r++) sT[r] = EXP2(sT[r] - MFIX);
  float ts[8];
#pragma unroll
  for (int r = 0; r < 8; r++) ts[r] = sT[r] + sT[r + 8];
#pragma unroll
  for (int r = 0; r < 4; r++) ts[r] = ts[r] + ts[r + 4];
  float sum = (ts[0] + ts[1]) + (ts[2] + ts[3]);
  sum = xhalf_sum(sum);
  l_run += sum;
  // pack P -> bf16 A-fragments: u[0]={a.lo|b.lo}, u[2]={a.hi|b.hi} (R4-verified)
#pragma unroll
  for (int kl = 0; kl < 2; kl++) {
    const int ra = 8 * kl;
    const int rb = 8 * kl + 4;
    unsigned int a0 = cvtpk(sT[ra + 0], sT[ra + 1]);
    unsigned int a1 = cvtpk(sT[ra + 2], sT[ra + 3]);
    unsigned int b0 = cvtpk(sT[rb + 0], sT[rb + 1]);
    unsigned int b1 = cvtpk(sT[rb + 2], sT[rb + 3]);
    plswap(a0, b0);
    plswap(a1, b1);
    union { short8 v; unsigned int u[4]; } pa;
    pa.u[0] = a0; pa.u[1] = a1; pa.u[2] = b0; pa.u[3] = b1;
    __builtin_amdgcn_s_setprio(1);
#pragma unroll
    for (int nt = 0; nt < 4; nt++) {
      short8 vf = *reinterpret_cast<const short8*>(vb + va[kl * 4 + nt]);
      acc[nt] = __builtin_amdgcn_mfma_f32_32x32x16_bf16(pa.v, vf, acc[nt], 0, 0, 0);
    }
    __builtin_amdgcn_s_setprio(0);
  }
}

// LDS: 2 buffers x (K 32KB + V 32KB) = 128KB; epilogue overlays 8x16KB partials
// at [0,128K) + l rows at 128K (1KB).
#define SMEM_BYTES 132096

struct WaveCtx {
  int w, lane, ln31, h, qs, kq, dstpart;
  int off[8];    // staging source offsets (pre-swizzled)
  int ka[8];     // hoisted K-fragment LDS offsets
  int va[8];     // hoisted V-fragment LDS offsets [kl*4+nt]
  const char* tbase;
};

// stage one 128-key tile (64KB total, 8KB per wave, imm=0)
DEVI void stage_tile(char* smem, const WaveCtx& c, const char* src, int bb) {
#pragma unroll
  for (int i = 0; i < 8; i++) {
    __builtin_amdgcn_global_load_lds(
        (const AS1 unsigned int*)(src + c.off[i]),
        (AS3 unsigned int*)(smem + bb + c.dstpart + i * 1024), 16, 0, 0);
  }
}

DEVI void run_strip(int j, int b, char* smem, const WaveCtx& c,
                    const float* __restrict__ Q, const float* __restrict__ SufV,
                    float* __restrict__ out) {
  const int q0 = j * 64;
  const int kv_end = q0 + 64;
  const int qrow = q0 + 32 * c.qs + c.ln31;
  const int T = (j >> 1) + 1;  // 128-key tiles

  // Q fragments (B-operand): frag kf element jj <-> d = 16*kf + 8*h + jj
  short8 qf[8];
  {
    const float* qsrc = Q + ((size_t)b * S_LEN + qrow) * D_DIM + 8 * c.h;
#pragma unroll
    for (int kf = 0; kf < 8; kf++) {
      float4 a = *reinterpret_cast<const float4*>(qsrc + 16 * kf);
      float4 d = *reinterpret_cast<const float4*>(qsrc + 16 * kf + 4);
      union { short8 v; unsigned int u[4]; } q8;
      q8.u[0] = cvtpk(a.x * QSC, a.y * QSC);
      q8.u[1] = cvtpk(a.z * QSC, a.w * QSC);
      q8.u[2] = cvtpk(d.x * QSC, d.y * QSC);
      q8.u[3] = cvtpk(d.z * QSC, d.w * QSC);
      qf[kf] = q8.v;
    }
  }

  f32x16 acc[4];
#pragma unroll
  for (int nt = 0; nt < 4; nt++)
#pragma unroll
    for (int rr = 0; rr < 16; rr++) acc[nt][rr] = 0.0f;
  float l_run = 0.0f;

  const char* kt0 = c.tbase;              // per-batch K base (32KB tiles)
  const char* vt0 = c.tbase + 0;          // placeholder; real bases passed below
  (void)vt0; (void)kt0;

  // main loop: R9 schedule (stage(next) || compute(cur); one barrier/phase)
  extern const char* __hip_unused;  // (no-op)
  stage_tile(smem, c, c.tbase + 0, 0);    // K-part waves use Kb base; V-part Vt
  __syncthreads();
  for (int t = 0; t < T; t++) {
    const int bb = (t & 1) << 16;
    if (t + 1 < T)
      stage_tile(smem, c, c.tbase + (size_t)(t + 1) * 32768, bb ^ 65536);
    const int kbq = 128 * t + 32 * c.kq;
    if (kbq < kv_end) {
      const char* kb = smem + bb;
      const char* vb = smem + bb + 32768;
      if (kbq + 31 > q0 + 32 * c.qs)
        tile_body<true>(kb, vb, c.ka, c.va, qf, acc, l_run, c.h, qrow, kbq);
      else
        tile_body<false>(kb, vb, c.ka, c.va, qf, acc, l_run, c.h, qrow, kbq);
    }
    __syncthreads();
  }

  // epilogue: all 8 waves write partial acc + l; wave kq==0 of each qs reduces
  float* pbase = (float*)smem + c.w * 4096;
#pragma unroll
  for (int nt = 0; nt < 4; nt++)
#pragma unroll
    for (int rr = 0; rr < 16; rr++) {
      int cr = (rr & 3) + 8 * (rr >> 2) + 4 * c.h;
      pbase[cr * 128 + c.ln31 + 32 * nt] = acc[nt][rr];
    }
  float* lbase = (float*)(smem + 131072) + c.w * 32;
  if (c.h == 0) lbase[c.ln31] = l_run;
  __syncthreads();

  const int s = c.w & 3;
  const float* P0 = (float*)smem + (c.qs * 4) * 4096;
  const float* L0 = (float*)(smem + 131072) + (c.qs * 4) * 32;
  float l_tot = L0[c.ln31] + L0[32 + c.ln31] + L0[64 + c.ln31] + L0[96 + c.ln31];
  l_tot += (float)(S_LEN - kv_end) * E8;
  const float svv = SufV[((size_t)b * 33 + (kv_end >> 6)) * 128 + 32 * s + c.ln31];
  float* ob = out + ((size_t)b * S_LEN + q0 + 32 * c.qs) * D_DIM + 32 * s + c.ln31;
#pragma unroll
  for (int rr = 0; rr < 16; rr++) {
    int cr = (rr & 3) + 8 * (rr >> 2) + 4 * c.h;
    int cidx = cr * 128 + 32 * s + c.ln31;
    float v = P0[cidx] + P0[4096 + cidx] + P0[8192 + cidx] + P0[12288 + cidx];
    float lq = __shfl(l_tot, cr);
    ob[(size_t)cr * D_DIM] = (v + E8 * svv) / lq;
  }
  __syncthreads();  // protect overlay before next strip's staging
}

__global__ __launch_bounds__(512, 2) void attn_kernel(
    const float* __restrict__ Q, const unsigned short* __restrict__ Kb,
    const unsigned short* __restrict__ Vt, const float* __restrict__ SufV,
    float* __restrict__ out) {
  __shared__ __align__(16) char smem[SMEM_BYTES];

  WaveCtx c;
  const int tid = threadIdx.x;
  c.w = tid >> 6;
  c.lane = tid & 63;
  c.ln31 = c.lane & 31;
  c.h = c.lane >> 5;
  c.qs = c.w >> 2;   // q half
  c.kq = c.w & 3;    // key quarter of the 128-key tile

  // decode: XCD x owns batches {2x,2x+1}; block = (b, pair p): strips 31-p and p
  const int bid = blockIdx.x;
  const int x = bid & 7, idx = bid >> 3;
  const int b = 2 * x + (idx & 1);
  const int p = idx >> 1;

  // staging: waves 0-3 (qs=0) stage K 32KB; waves 4-7 stage V^T 32KB.
  // 256B rows, 16-slot XOR swizzle pre-applied on the source (involution).
  const int part = c.w & 3;
#pragma unroll
  for (int i = 0; i < 8; i++) {
    int L = (part * 8 + i) * 1024 + c.lane * 16;
    int row = L >> 8;
    c.off[i] = row * 256 + ((L & 255) ^ ((row & 15) << 4));
  }
  if (c.w < 4) {
    c.tbase = (const char*)(Kb + (size_t)b * S_LEN * D_DIM);
    c.dstpart = part * 8192;
  } else {
    c.tbase = (const char*)Vt + (size_t)b * (S_LEN * D_DIM * 2);
    c.dstpart = 32768 + part * 8192;
  }

  // hoisted fragment addresses (read-side XOR matches staging pre-swizzle)
  {
    const int krow = 32 * c.kq + c.ln31;
    const int ksw = (krow & 15) << 4;
#pragma unroll
    for (int kf = 0; kf < 8; kf++)
      c.ka[kf] = krow * 256 + ((32 * kf + 16 * c.h) ^ ksw);
    const int vsw = (c.ln31 & 15) << 4;  // (ln31+32nt)&15 == ln31&15
#pragma unroll
    for (int kl = 0; kl < 2; kl++)
#pragma unroll
      for (int nt = 0; nt < 4; nt++)
        c.va[kl * 4 + nt] = (c.ln31 + 32 * nt) * 256 +
                            ((64 * c.kq + 32 * kl + 16 * c.h) ^ vsw);
  }

  run_strip(31 - p, b, smem, c, Q, SufV, out);
  run_strip(p, b, smem, c, Q, SufV, out);
}

// ---------------- launcher ----------------

extern "C" void kernel_launch(void* const* d_in, const int* in_sizes, int n_in,
                              void* d_out, int out_size, void* d_ws, size_t ws_size,
                              hipStream_t stream) {
  const float* Q = (const float*)d_in[0];
  const float* K = (const float*)d_in[1];
  const float* V = (const float*)d_in[2];
  float* out = (float*)d_out;

  char* ws = (char*)d_ws;
  unsigned short* Kb = (unsigned short*)ws;                 // 8 MiB
  unsigned short* Vt = Kb + 4194304;                        // 8 MiB (128-tile-major)
  float* Tsum = (float*)(ws + 16777216);                    // 256 KiB
  float* SufV = Tsum + 65536;                               // 264 KiB

  prep<<<3072, 256, 0, stream>>>(K, V, Kb, Vt, Tsum);
  sufB<<<16, 128, 0, stream>>>(Tsum, SufV);
  attn_kernel<<<256, 512, 0, stream>>>(Q, Kb, Vt, SufV, out);
}